// Round 2
// baseline (1983.956 us; speedup 1.0000x reference)
//
#include <hip/hip_runtime.h>

typedef __bf16 bf16;
typedef __bf16 bf16x8 __attribute__((ext_vector_type(8)));
typedef __bf16 bf16x4 __attribute__((ext_vector_type(4)));
typedef float floatx4 __attribute__((ext_vector_type(4)));

#define T_TOK 8192          // B*S tokens
#define SEQ 2048
#define NHEAD 12
#define SM_SCALE 0.07216878364870323f   // 192^-0.5

// ============================ prep kernels ============================
__global__ __launch_bounds__(256) void cast_f32_bf16(const float* __restrict__ in,
                                                     bf16* __restrict__ out, long n4) {
  long i = (long)blockIdx.x * 256 + threadIdx.x;
  if (i >= n4) return;
  float4 v = ((const float4*)in)[i];
  bf16x4 o;
  o[0] = (bf16)v.x; o[1] = (bf16)v.y; o[2] = (bf16)v.z; o[3] = (bf16)v.w;
  ((bf16x4*)out)[i] = o;
}

// wkv_a (576,1024) -> bf16 padded to (640,1024), pad rows zeroed
__global__ __launch_bounds__(256) void cast_wkva_pad(const float* __restrict__ in,
                                                     bf16* __restrict__ out) {
  long i = (long)blockIdx.x * 256 + threadIdx.x;   // 4-elem chunks, 640*256 total
  int r = (int)(i >> 8);
  bf16x4 o;
  if (r < 576) {
    float4 v = ((const float4*)in)[i];
    o[0] = (bf16)v.x; o[1] = (bf16)v.y; o[2] = (bf16)v.z; o[3] = (bf16)v.w;
  } else {
    o[0] = (bf16)0.f; o[1] = (bf16)0.f; o[2] = (bf16)0.f; o[3] = (bf16)0.f;
  }
  ((bf16x4*)out)[i] = o;
}

// wkv_b (12*256, 512): d<128 -> wbnT[h][c][d] (transposed), d>=128 -> wbv[h][d-128][c]
__global__ __launch_bounds__(256) void split_wkvb(const float* __restrict__ in,
                                                  bf16* __restrict__ wbnT,
                                                  bf16* __restrict__ wbv) {
  int i = blockIdx.x * 256 + threadIdx.x;          // < 12*256*512
  int h = i >> 17, rem = i & 131071, d = rem >> 9, c = rem & 511;
  bf16 v = (bf16)in[i];
  if (d < 128) wbnT[((h * 512 + c) << 7) + d] = v;
  else         wbv[((h * 128 + (d - 128)) << 9) + c] = v;
}

// ============================ GEMM: C[M,N] = A[M,K] * B[N,K]^T ============================
// MODE 0: fp32 C.  MODE 1: bf16 C.  MODE 2: q-epilogue (rope q_pe -> qabs, scale q_nope -> qn)
// MODE 3: bf16 C^T (C[cc][rr], ldc = out row stride)
template <int MODE>
__global__ __launch_bounds__(256) void gemm_bt(
    const bf16* __restrict__ A, const bf16* __restrict__ B, void* __restrict__ Cv,
    int N, int K, int lda, int ldb, int ldc,
    long sA, long sB, long sC,
    const float* __restrict__ freqs, bf16* __restrict__ qn, bf16* __restrict__ qabs) {
  __shared__ alignas(16) bf16 As[128 * 32];
  __shared__ alignas(16) bf16 Bs[128 * 32];
  const int z = blockIdx.z;
  A += (long)z * sA;  B += (long)z * sB;
  const int row0 = blockIdx.y * 128, col0 = blockIdx.x * 128;
  const int tid = threadIdx.x;
  const int w = tid >> 6, l = tid & 63, lm = l & 15, quad = l >> 4;
  const int wr = w >> 1, wc = w & 1;
  floatx4 acc[4][4] = {};

  for (int k0 = 0; k0 < K; k0 += 32) {
    __syncthreads();
#pragma unroll
    for (int i = 0; i < 2; i++) {
      int cid = i * 256 + tid;
      int r = cid >> 2, c8 = (cid & 3) * 8;
      *(bf16x8*)(As + r * 32 + c8) = *(const bf16x8*)(A + (long)(row0 + r) * lda + k0 + c8);
      *(bf16x8*)(Bs + r * 32 + c8) = *(const bf16x8*)(B + (long)(col0 + r) * ldb + k0 + c8);
    }
    __syncthreads();
    bf16x8 af[4], bfr[4];
#pragma unroll
    for (int i = 0; i < 4; i++) {
      af[i]  = *(const bf16x8*)(As + (wr * 64 + i * 16 + lm) * 32 + quad * 8);
      bfr[i] = *(const bf16x8*)(Bs + (wc * 64 + i * 16 + lm) * 32 + quad * 8);
    }
#pragma unroll
    for (int i = 0; i < 4; i++)
#pragma unroll
      for (int j = 0; j < 4; j++)
        acc[i][j] = __builtin_amdgcn_mfma_f32_16x16x32_bf16(af[i], bfr[j], acc[i][j], 0, 0, 0);
  }

#pragma unroll
  for (int i = 0; i < 4; i++) {
#pragma unroll
    for (int j = 0; j < 4; j++) {
#pragma unroll
      for (int r = 0; r < 4; r++) {
        float val = acc[i][j][r];
        float partner = __shfl_xor(val, 1, 64);  // unconditional: lane pair = adjacent column
        int rr = row0 + wr * 64 + i * 16 + quad * 4 + r;
        int cc = col0 + wc * 64 + j * 16 + lm;
        if (cc < N) {
          if (MODE == 0) {
            ((float*)Cv + (long)z * sC)[(long)rr * ldc + cc] = val;
          } else if (MODE == 1) {
            ((bf16*)Cv + (long)z * sC)[(long)rr * ldc + cc] = (bf16)val;
          } else if (MODE == 3) {
            ((bf16*)Cv + (long)z * sC)[(long)cc * ldc + rr] = (bf16)val;
          } else {
            int s = rr & (SEQ - 1);
            int h = cc / 192, wi = cc % 192;
            if (wi < 128) {
              qn[((long)h * T_TOK + rr) * 128 + wi] = (bf16)(val * SM_SCALE);
            } else {
              int pp = (wi - 128) >> 1;
              float cs = freqs[s * 64 + pp * 2], sn = freqs[s * 64 + pp * 2 + 1];
              float res = ((wi & 1) == 0) ? (val * cs - partner * sn)
                                          : (partner * sn + val * cs);
              qabs[((long)h * T_TOK + rr) * 576 + 512 + (wi - 128)] = (bf16)(res * SM_SCALE);
            }
          }
        }
      }
    }
  }
}

// ================= rmsnorm(kv) + rope(k_pe) -> K' bf16 (8192 x 576) =================
__global__ __launch_bounds__(64) void kvnorm_rope(const float* __restrict__ kvf,
                                                  const float* __restrict__ wnorm,
                                                  const float* __restrict__ freqs,
                                                  bf16* __restrict__ Kp) {
  const int t = blockIdx.x, l = threadIdx.x, s = t & (SEQ - 1);
  const float* row = kvf + (long)t * 576;
  float4 a4 = ((const float4*)row)[l * 2];
  float4 b4 = ((const float4*)row)[l * 2 + 1];
  float v[8] = {a4.x, a4.y, a4.z, a4.w, b4.x, b4.y, b4.z, b4.w};
  float ssq = 0.f;
#pragma unroll
  for (int i = 0; i < 8; i++) ssq += v[i] * v[i];
#pragma unroll
  for (int m = 1; m < 64; m <<= 1) ssq += __shfl_xor(ssq, m, 64);
  const float rn = rsqrtf(ssq * (1.f / 512.f) + 1e-6f);
  bf16x8 o;
#pragma unroll
  for (int i = 0; i < 8; i++) o[i] = (bf16)(v[i] * rn * wnorm[l * 8 + i]);
  *(bf16x8*)(Kp + (long)t * 576 + l * 8) = o;
  if (l < 32) {
    float xr = row[512 + 2 * l], xi = row[513 + 2 * l];
    float cs = freqs[s * 64 + 2 * l], sn = freqs[s * 64 + 2 * l + 1];
    Kp[(long)t * 576 + 512 + 2 * l] = (bf16)(xr * cs - xi * sn);
    Kp[(long)t * 576 + 513 + 2 * l] = (bf16)(xr * sn + xi * cs);
  }
}

// ============================ flash MLA attention (v2) ============================
// grid (32 qtiles, 12 heads, 4 batch), 256 thr. BM=BN=64. Q' pre-scaled by SM_SCALE.
// K and Vp fragments read directly from global (L1/L2-served); LDS only for P^T + softmax state.
__global__ __launch_bounds__(256, 2) void mla_attn(const bf16* __restrict__ qabs,
                                                   const bf16* __restrict__ Kp,
                                                   const bf16* __restrict__ VpT,
                                                   bf16* __restrict__ o_all) {
  constexpr int PROW = 72;   // 64+8 pad -> 2-way bank alias (free)
  __shared__ alignas(16) bf16 Ps[64 * PROW];
  __shared__ float alpha_s[64];
  __shared__ float l_s[64];

  const int qi = (int)(gridDim.x - 1 - blockIdx.x);  // big tiles first
  const int h = blockIdx.y, b = blockIdx.z;
  const int tid = threadIdx.x, w = tid >> 6, l = tid & 63;
  const int lm = l & 15, quad = l >> 4;
  const long tq0 = (long)b * SEQ + (long)qi * 64;

  // persistent Q fragments: wave w owns q-rows [w*16, w*16+16) as MFMA B-operand (n=lm)
  bf16x8 qf[18];
  {
    const bf16* qb = qabs + ((long)h * T_TOK + tq0 + w * 16 + lm) * 576 + quad * 8;
#pragma unroll
    for (int kk = 0; kk < 18; kk++) qf[kk] = *(const bf16x8*)(qb + kk * 32);
  }
  floatx4 oacc[4][2] = {};   // [q m-tile][d n-tile]; wave owns d-strip w*32..+32, all 64 q
  float mstate = -__builtin_inff(), lstate = 0.f;  // for q column w*16+lm (quad-replicated)

  for (int kt = 0; kt <= qi; kt++) {
    const long tk0 = (long)b * SEQ + (long)kt * 64;
    // S^T strip: m = t (4 tiles of 16), n = this wave's 16 q columns.
    // K fragments straight from global: per instr, 16 rows x 64B contiguous.
    const bf16* kb = Kp + (tk0 + lm) * 576 + quad * 8;
    floatx4 sacc[4] = {};
#pragma unroll
    for (int kk = 0; kk < 18; kk++) {
      bf16x8 kf[4];
#pragma unroll
      for (int i = 0; i < 4; i++)
        kf[i] = *(const bf16x8*)(kb + (long)(i * 16) * 576 + kk * 32);
#pragma unroll
      for (int i = 0; i < 4; i++)
        sacc[i] = __builtin_amdgcn_mfma_f32_16x16x32_bf16(kf[i], qf[kk], sacc[i], 0, 0, 0);
    }
    if (kt == qi) {  // causal mask inside diagonal tile: t_local > q_local
#pragma unroll
      for (int i = 0; i < 4; i++)
#pragma unroll
        for (int r = 0; r < 4; r++)
          if (i * 16 + quad * 4 + r > w * 16 + lm) sacc[i][r] = -__builtin_inff();
    }
    // online softmax per q column
    float cmax = -__builtin_inff();
#pragma unroll
    for (int i = 0; i < 4; i++)
#pragma unroll
      for (int r = 0; r < 4; r++) cmax = fmaxf(cmax, sacc[i][r]);
    cmax = fmaxf(cmax, __shfl_xor(cmax, 16, 64));
    cmax = fmaxf(cmax, __shfl_xor(cmax, 32, 64));
    const float mnew = fmaxf(mstate, cmax);
    const float alpha = __expf(mstate - mnew);
    float psum = 0.f;
#pragma unroll
    for (int i = 0; i < 4; i++) {
      bf16x4 pw;
#pragma unroll
      for (int r = 0; r < 4; r++) {
        float pv = __expf(sacc[i][r] - mnew);
        psum += pv;
        pw[r] = (bf16)pv;
      }
      // P^T -> Ps[q][t]; 4 consecutive t per reg group -> b64 write
      *(bf16x4*)(Ps + (w * 16 + lm) * PROW + i * 16 + quad * 4) = pw;
    }
    psum += __shfl_xor(psum, 16, 64);
    psum += __shfl_xor(psum, 32, 64);
    lstate = lstate * alpha + psum;
    mstate = mnew;
    if (l < 16) alpha_s[w * 16 + l] = alpha;
    __syncthreads();

    // rescale O, then O += P * Vp (wave owns d-strip w*32; Vp frags from global)
#pragma unroll
    for (int mi = 0; mi < 4; mi++)
#pragma unroll
      for (int r = 0; r < 4; r++) {
        const float a = alpha_s[mi * 16 + quad * 4 + r];
#pragma unroll
        for (int nj = 0; nj < 2; nj++) oacc[mi][nj][r] *= a;
      }
    const bf16* vbase = VpT + ((long)h * 128 + w * 32 + lm) * (long)T_TOK +
                        (long)b * SEQ + kt * 64 + quad * 8;
#pragma unroll
    for (int ks = 0; ks < 2; ks++) {
      bf16x8 vb[2];
#pragma unroll
      for (int nj = 0; nj < 2; nj++)
        vb[nj] = *(const bf16x8*)(vbase + (long)(nj * 16) * T_TOK + ks * 32);
#pragma unroll
      for (int mi = 0; mi < 4; mi++) {
        bf16x8 pa = *(const bf16x8*)(Ps + (mi * 16 + lm) * PROW + ks * 32 + quad * 8);
#pragma unroll
        for (int nj = 0; nj < 2; nj++)
          oacc[mi][nj] = __builtin_amdgcn_mfma_f32_16x16x32_bf16(pa, vb[nj], oacc[mi][nj], 0, 0, 0);
      }
    }
    __syncthreads();
  }

  // epilogue: scale by 1/l and store (V-projection already folded into VpT)
  if (l < 16) l_s[w * 16 + l] = lstate;
  __syncthreads();
#pragma unroll
  for (int mi = 0; mi < 4; mi++) {
#pragma unroll
    for (int r = 0; r < 4; r++) {
      const int q = mi * 16 + quad * 4 + r;
      const float inv = 1.f / l_s[q];
#pragma unroll
      for (int nj = 0; nj < 2; nj++)
        o_all[(tq0 + q) * 1536 + h * 128 + w * 32 + nj * 16 + lm] = (bf16)(oacc[mi][nj][r] * inv);
    }
  }
}

// ============================ launcher ============================
extern "C" void kernel_launch(void* const* d_in, const int* in_sizes, int n_in,
                              void* d_out, int out_size, void* d_ws, size_t ws_size,
                              hipStream_t stream) {
  (void)in_sizes; (void)n_in; (void)out_size; (void)ws_size;
  const float* x     = (const float*)d_in[0];
  const float* wq    = (const float*)d_in[1];
  const float* wkva  = (const float*)d_in[2];
  const float* kvnw  = (const float*)d_in[3];
  const float* wkvb  = (const float*)d_in[4];
  const float* wo    = (const float*)d_in[5];
  const float* freqs = (const float*)d_in[6];
  float* out = (float*)d_out;

  char* p = (char*)d_ws;
  auto alloc = [&](size_t bytes) {
    char* r = p;
    p += (bytes + 255) & ~(size_t)255;
    return r;
  };
  bf16*  xb    = (bf16*) alloc((size_t)T_TOK * 1024 * 2);
  bf16*  wqb   = (bf16*) alloc((size_t)2304 * 1024 * 2);
  bf16*  wkvab = (bf16*) alloc((size_t)640 * 1024 * 2);     // padded N 576->640
  bf16*  wbnT  = (bf16*) alloc((size_t)12 * 512 * 128 * 2);
  bf16*  wbv   = (bf16*) alloc((size_t)12 * 128 * 512 * 2);
  bf16*  wob   = (bf16*) alloc((size_t)1024 * 1536 * 2);
  float* kvf   = (float*)alloc((size_t)T_TOK * 576 * 4);
  bf16*  Kp    = (bf16*) alloc((size_t)T_TOK * 576 * 2);
  bf16*  VpT   = (bf16*) alloc((size_t)12 * 128 * T_TOK * 2);
  bf16*  qn    = (bf16*) alloc((size_t)12 * T_TOK * 128 * 2);
  bf16*  qabs  = (bf16*) alloc((size_t)12 * T_TOK * 576 * 2);
  bf16*  o_all = (bf16*) alloc((size_t)T_TOK * 1536 * 2);

  cast_f32_bf16<<<8192, 256, 0, stream>>>(x, xb, (long)T_TOK * 1024 / 4);
  cast_f32_bf16<<<2304, 256, 0, stream>>>(wq, wqb, (long)2304 * 1024 / 4);
  cast_wkva_pad<<<640, 256, 0, stream>>>(wkva, wkvab);
  split_wkvb<<<6144, 256, 0, stream>>>(wkvb, wbnT, wbv);
  cast_f32_bf16<<<1536, 256, 0, stream>>>(wo, wob, (long)1024 * 1536 / 4);

  // kv_full = x @ wkv_a^T  (fp32 out)
  gemm_bt<0><<<dim3(5, 64, 1), 256, 0, stream>>>(xb, wkvab, (void*)kvf, 576, 1024,
      1024, 1024, 576, 0, 0, 0, nullptr, nullptr, nullptr);
  // q = x @ wq^T, fused rope(q_pe)+scale epilogue -> qn, qabs[512:576]
  gemm_bt<2><<<dim3(18, 64, 1), 256, 0, stream>>>(xb, wqb, nullptr, 2304, 1024,
      1024, 1024, 0, 0, 0, 0, freqs, qn, qabs);
  kvnorm_rope<<<T_TOK, 64, 0, stream>>>(kvf, kvnw, freqs, Kp);
  // VpT[h][d][t] = (kv_c @ wbv[h]^T)^T  (batched over heads, transposed bf16 write)
  gemm_bt<3><<<dim3(1, 64, 12), 256, 0, stream>>>(Kp, wbv, (void*)VpT, 128, 512,
      576, 512, T_TOK, 0, (long)128 * 512, (long)128 * T_TOK,
      nullptr, nullptr, nullptr);
  // q_abs[h] = qn[h] @ wbnT[h]^T  (batched over heads, bf16 out into qabs[0:512])
  gemm_bt<1><<<dim3(4, 64, 12), 256, 0, stream>>>(qn, wbnT, (void*)qabs, 512, 128,
      128, 128, 576, (long)T_TOK * 128, (long)512 * 128, (long)T_TOK * 576,
      nullptr, nullptr, nullptr);
  mla_attn<<<dim3(32, 12, 4), 256, 0, stream>>>(qabs, Kp, VpT, o_all);
  // out = o_all @ wo^T (fp32 out)
  gemm_bt<0><<<dim3(8, 64, 1), 256, 0, stream>>>(o_all, wob, (void*)out, 1024, 1536,
      1536, 1536, 1024, 0, 0, 0, nullptr, nullptr, nullptr);
}

// Round 3
// 768.262 us; speedup vs baseline: 2.5824x; 2.5824x over previous
//
#include <hip/hip_runtime.h>

typedef __bf16 bf16;
typedef __bf16 bf16x8 __attribute__((ext_vector_type(8)));
typedef __bf16 bf16x4 __attribute__((ext_vector_type(4)));
typedef float floatx4 __attribute__((ext_vector_type(4)));

#define T_TOK 8192          // B*S tokens
#define SEQ 2048
#define KLD 584             // padded Kp leading dim (1168 B rows; bank stride 4 => conflict-free frags)
#define SM_SCALE 0.07216878364870323f   // 192^-0.5

// async global->LDS, 16B per lane; LDS dest is wave-uniform base + lane*16 (linear)
__device__ __forceinline__ void dma16(const void* g, void* l) {
  __builtin_amdgcn_global_load_lds(
      (const __attribute__((address_space(1))) unsigned int*)g,
      (__attribute__((address_space(3))) unsigned int*)l, 16, 0, 0);
}

// ============================ prep kernels ============================
__global__ __launch_bounds__(256) void cast_f32_bf16(const float* __restrict__ in,
                                                     bf16* __restrict__ out, long n4) {
  long i = (long)blockIdx.x * 256 + threadIdx.x;
  if (i >= n4) return;
  float4 v = ((const float4*)in)[i];
  bf16x4 o;
  o[0] = (bf16)v.x; o[1] = (bf16)v.y; o[2] = (bf16)v.z; o[3] = (bf16)v.w;
  ((bf16x4*)out)[i] = o;
}

// wkv_a (576,1024) -> bf16 padded to (640,1024), pad rows zeroed
__global__ __launch_bounds__(256) void cast_wkva_pad(const float* __restrict__ in,
                                                     bf16* __restrict__ out) {
  long i = (long)blockIdx.x * 256 + threadIdx.x;   // 4-elem chunks, 640*256 total
  int r = (int)(i >> 8);
  bf16x4 o;
  if (r < 576) {
    float4 v = ((const float4*)in)[i];
    o[0] = (bf16)v.x; o[1] = (bf16)v.y; o[2] = (bf16)v.z; o[3] = (bf16)v.w;
  } else {
    o[0] = (bf16)0.f; o[1] = (bf16)0.f; o[2] = (bf16)0.f; o[3] = (bf16)0.f;
  }
  ((bf16x4*)out)[i] = o;
}

// wkv_b (12*256, 512): d<128 -> wbnT[h][c][d] (transposed), d>=128 -> wbv[h][d-128][c]
__global__ __launch_bounds__(256) void split_wkvb(const float* __restrict__ in,
                                                  bf16* __restrict__ wbnT,
                                                  bf16* __restrict__ wbv) {
  int i = blockIdx.x * 256 + threadIdx.x;          // < 12*256*512
  int h = i >> 17, rem = i & 131071, d = rem >> 9, c = rem & 511;
  bf16 v = (bf16)in[i];
  if (d < 128) wbnT[((h * 512 + c) << 7) + d] = v;
  else         wbv[((h * 128 + (d - 128)) << 9) + c] = v;
}

// ============================ GEMM: C[M,N] = A[M,K] * B[N,K]^T ============================
// MODE 0: fp32 C.  MODE 1: bf16 C.  MODE 2: q-epilogue (rope q_pe -> qabs, scale q_nope -> qn)
// MODE 3: bf16 C^T (C[cc][rr], ldc = out row stride)
template <int MODE>
__global__ __launch_bounds__(256) void gemm_bt(
    const bf16* __restrict__ A, const bf16* __restrict__ B, void* __restrict__ Cv,
    int N, int K, int lda, int ldb, int ldc,
    long sA, long sB, long sC,
    const float* __restrict__ freqs, bf16* __restrict__ qn, bf16* __restrict__ qabs) {
  __shared__ alignas(16) bf16 As[128 * 32];
  __shared__ alignas(16) bf16 Bs[128 * 32];
  const int z = blockIdx.z;
  A += (long)z * sA;  B += (long)z * sB;
  const int row0 = blockIdx.y * 128, col0 = blockIdx.x * 128;
  const int tid = threadIdx.x;
  const int w = tid >> 6, l = tid & 63, lm = l & 15, quad = l >> 4;
  const int wr = w >> 1, wc = w & 1;
  floatx4 acc[4][4] = {};

  for (int k0 = 0; k0 < K; k0 += 32) {
    __syncthreads();
#pragma unroll
    for (int i = 0; i < 2; i++) {
      int cid = i * 256 + tid;
      int r = cid >> 2, c8 = (cid & 3) * 8;
      *(bf16x8*)(As + r * 32 + c8) = *(const bf16x8*)(A + (long)(row0 + r) * lda + k0 + c8);
      *(bf16x8*)(Bs + r * 32 + c8) = *(const bf16x8*)(B + (long)(col0 + r) * ldb + k0 + c8);
    }
    __syncthreads();
    bf16x8 af[4], bfr[4];
#pragma unroll
    for (int i = 0; i < 4; i++) {
      af[i]  = *(const bf16x8*)(As + (wr * 64 + i * 16 + lm) * 32 + quad * 8);
      bfr[i] = *(const bf16x8*)(Bs + (wc * 64 + i * 16 + lm) * 32 + quad * 8);
    }
#pragma unroll
    for (int i = 0; i < 4; i++)
#pragma unroll
      for (int j = 0; j < 4; j++)
        acc[i][j] = __builtin_amdgcn_mfma_f32_16x16x32_bf16(af[i], bfr[j], acc[i][j], 0, 0, 0);
  }

#pragma unroll
  for (int i = 0; i < 4; i++) {
#pragma unroll
    for (int j = 0; j < 4; j++) {
#pragma unroll
      for (int r = 0; r < 4; r++) {
        float val = acc[i][j][r];
        float partner = __shfl_xor(val, 1, 64);  // unconditional: lane pair = adjacent column
        int rr = row0 + wr * 64 + i * 16 + quad * 4 + r;
        int cc = col0 + wc * 64 + j * 16 + lm;
        if (cc < N) {
          if (MODE == 0) {
            ((float*)Cv + (long)z * sC)[(long)rr * ldc + cc] = val;
          } else if (MODE == 1) {
            ((bf16*)Cv + (long)z * sC)[(long)rr * ldc + cc] = (bf16)val;
          } else if (MODE == 3) {
            ((bf16*)Cv + (long)z * sC)[(long)cc * ldc + rr] = (bf16)val;
          } else {
            int s = rr & (SEQ - 1);
            int h = cc / 192, wi = cc % 192;
            if (wi < 128) {
              qn[((long)h * T_TOK + rr) * 128 + wi] = (bf16)(val * SM_SCALE);
            } else {
              int pp = (wi - 128) >> 1;
              float cs = freqs[s * 64 + pp * 2], sn = freqs[s * 64 + pp * 2 + 1];
              float res = ((wi & 1) == 0) ? (val * cs - partner * sn)
                                          : (partner * sn + val * cs);
              qabs[((long)h * T_TOK + rr) * 576 + 512 + (wi - 128)] = (bf16)(res * SM_SCALE);
            }
          }
        }
      }
    }
  }
}

// ================= rmsnorm(kv) + rope(k_pe) -> K' bf16 (8192 x 576, ld=KLD) =================
__global__ __launch_bounds__(64) void kvnorm_rope(const float* __restrict__ kvf,
                                                  const float* __restrict__ wnorm,
                                                  const float* __restrict__ freqs,
                                                  bf16* __restrict__ Kp) {
  const int t = blockIdx.x, l = threadIdx.x, s = t & (SEQ - 1);
  const float* row = kvf + (long)t * 576;
  float4 a4 = ((const float4*)row)[l * 2];
  float4 b4 = ((const float4*)row)[l * 2 + 1];
  float v[8] = {a4.x, a4.y, a4.z, a4.w, b4.x, b4.y, b4.z, b4.w};
  float ssq = 0.f;
#pragma unroll
  for (int i = 0; i < 8; i++) ssq += v[i] * v[i];
#pragma unroll
  for (int m = 1; m < 64; m <<= 1) ssq += __shfl_xor(ssq, m, 64);
  const float rn = rsqrtf(ssq * (1.f / 512.f) + 1e-6f);
  bf16x8 o;
#pragma unroll
  for (int i = 0; i < 8; i++) o[i] = (bf16)(v[i] * rn * wnorm[l * 8 + i]);
  *(bf16x8*)(Kp + (long)t * KLD + l * 8) = o;
  if (l < 32) {
    float xr = row[512 + 2 * l], xi = row[513 + 2 * l];
    float cs = freqs[s * 64 + 2 * l], sn = freqs[s * 64 + 2 * l + 1];
    Kp[(long)t * KLD + 512 + 2 * l] = (bf16)(xr * cs - xi * sn);
    Kp[(long)t * KLD + 513 + 2 * l] = (bf16)(xr * sn + xi * cs);
  }
}

// ============================ flash MLA attention (v3) ============================
// block = (qt16, head-group g of 4, b); wave w = head g*4+w, 16 q-cols. BN=32 kt.
// K-tile DMA'd to LDS (global_load_lds, padded rows). V frags from global VpT in PV phase.
__global__ __launch_bounds__(256, 3) void mla_attn(const bf16* __restrict__ qabs,
                                                   const bf16* __restrict__ Kp,
                                                   const bf16* __restrict__ VpT,
                                                   bf16* __restrict__ o_all) {
  constexpr int PROW = 40;                    // 32+8 pad
  __shared__ alignas(16) bf16 Ks[19456];      // 37 KB K-tile (32 rows x KLD) + DMA slack
  __shared__ alignas(16) bf16 Ps[64 * PROW];
  __shared__ float alpha_s[64];
  __shared__ float l_s[64];

  const int qt = 127 - (int)blockIdx.x;       // big q-tiles first
  const int g = blockIdx.y, b = blockIdx.z;
  const int tid = threadIdx.x, w = tid >> 6, l = tid & 63;
  const int lm = l & 15, quad = l >> 4;
  const int h = g * 4 + w;                    // this wave's head
  const long tq0 = (long)b * SEQ + qt * 16;

  // persistent Q fragments (B-operand, n=lm = q-col within this wave's head)
  bf16x8 qf[18];
  {
    const bf16* qb = qabs + ((long)h * T_TOK + tq0 + lm) * 576 + quad * 8;
#pragma unroll
    for (int kk = 0; kk < 18; kk++) qf[kk] = *(const bf16x8*)(qb + kk * 32);
  }
  floatx4 oacc[4][2] = {};                    // [head m-tile][d n-tile]; wave d-strip w*32
  float mstate = -__builtin_inff(), lstate = 0.f;
  const int nk = (qt >> 1) + 1;
  const int moff = (qt & 1) * 16;

  for (int kt = 0; kt < nk; kt++) {
    {  // DMA K-tile: 32 padded rows = 37376 B linear in global (Kp ld=KLD)
      const char* gk = (const char*)(Kp + ((long)b * SEQ + kt * 32) * KLD);
      for (int j = w; j < 37; j += 4)
        dma16(gk + j * 1024 + l * 16, (char*)Ks + j * 1024);
    }
    __syncthreads();  // drains DMA (vmcnt0) ; also: all waves done with prev PV (Ps free)

    // S^T strip: m = t (2 tiles of 16), n = this wave's 16 q columns
    floatx4 sacc[2] = {};
#pragma unroll
    for (int kk = 0; kk < 18; kk++) {
      bf16x8 kf0 = *(const bf16x8*)(Ks + lm * KLD + kk * 32 + quad * 8);
      bf16x8 kf1 = *(const bf16x8*)(Ks + (16 + lm) * KLD + kk * 32 + quad * 8);
      sacc[0] = __builtin_amdgcn_mfma_f32_16x16x32_bf16(kf0, qf[kk], sacc[0], 0, 0, 0);
      sacc[1] = __builtin_amdgcn_mfma_f32_16x16x32_bf16(kf1, qf[kk], sacc[1], 0, 0, 0);
    }
    if (kt == nk - 1) {  // causal mask: t_local > q_local (q_local = moff + lm)
#pragma unroll
      for (int i = 0; i < 2; i++)
#pragma unroll
        for (int r = 0; r < 4; r++)
          if (i * 16 + quad * 4 + r > moff + lm) sacc[i][r] = -__builtin_inff();
    }
    // online softmax per q column (stats replicated across quads via shfl)
    float cmax = -__builtin_inff();
#pragma unroll
    for (int i = 0; i < 2; i++)
#pragma unroll
      for (int r = 0; r < 4; r++) cmax = fmaxf(cmax, sacc[i][r]);
    cmax = fmaxf(cmax, __shfl_xor(cmax, 16, 64));
    cmax = fmaxf(cmax, __shfl_xor(cmax, 32, 64));
    const float mnew = fmaxf(mstate, cmax);
    const float alpha = __expf(mstate - mnew);
    float psum = 0.f;
#pragma unroll
    for (int i = 0; i < 2; i++) {
      bf16x4 pw;
#pragma unroll
      for (int r = 0; r < 4; r++) {
        float pv = __expf(sacc[i][r] - mnew);
        psum += pv;
        pw[r] = (bf16)pv;
      }
      *(bf16x4*)(Ps + (w * 16 + lm) * PROW + i * 16 + quad * 4) = pw;  // P^T -> Ps[q][t]
    }
    psum += __shfl_xor(psum, 16, 64);
    psum += __shfl_xor(psum, 32, 64);
    lstate = lstate * alpha + psum;
    mstate = mnew;
    if (l < 16) alpha_s[w * 16 + l] = alpha;
    __syncthreads();  // Ps/alpha visible; all Ks frag reads done (safe for next DMA)

    // PV: rescale O, then O += P * Vp (V frags from global; 8 independent loads)
#pragma unroll
    for (int mi = 0; mi < 4; mi++) {
#pragma unroll
      for (int r = 0; r < 4; r++) {
        const float a = alpha_s[mi * 16 + quad * 4 + r];
        oacc[mi][0][r] *= a;
        oacc[mi][1][r] *= a;
      }
    }
    const long tv = (long)b * SEQ + kt * 32 + quad * 8;
#pragma unroll
    for (int mi = 0; mi < 4; mi++) {
      const bf16* vrow = VpT + ((long)((g * 4 + mi) * 128 + w * 32 + lm)) * T_TOK + tv;
      bf16x8 vb0 = *(const bf16x8*)(vrow);
      bf16x8 vb1 = *(const bf16x8*)(vrow + (long)16 * T_TOK);
      bf16x8 pa = *(const bf16x8*)(Ps + (mi * 16 + lm) * PROW + quad * 8);
      oacc[mi][0] = __builtin_amdgcn_mfma_f32_16x16x32_bf16(pa, vb0, oacc[mi][0], 0, 0, 0);
      oacc[mi][1] = __builtin_amdgcn_mfma_f32_16x16x32_bf16(pa, vb1, oacc[mi][1], 0, 0, 0);
    }
  }

  // epilogue: scale by 1/l and store
  if (l < 16) l_s[w * 16 + l] = lstate;
  __syncthreads();
#pragma unroll
  for (int mi = 0; mi < 4; mi++) {
#pragma unroll
    for (int r = 0; r < 4; r++) {
      const int qrow = quad * 4 + r;
      const float inv = 1.f / l_s[mi * 16 + qrow];
#pragma unroll
      for (int nj = 0; nj < 2; nj++)
        o_all[(tq0 + qrow) * 1536 + (g * 4 + mi) * 128 + w * 32 + nj * 16 + lm] =
            (bf16)(oacc[mi][nj][r] * inv);
    }
  }
}

// ============================ launcher ============================
extern "C" void kernel_launch(void* const* d_in, const int* in_sizes, int n_in,
                              void* d_out, int out_size, void* d_ws, size_t ws_size,
                              hipStream_t stream) {
  (void)in_sizes; (void)n_in; (void)out_size; (void)ws_size;
  const float* x     = (const float*)d_in[0];
  const float* wq    = (const float*)d_in[1];
  const float* wkva  = (const float*)d_in[2];
  const float* kvnw  = (const float*)d_in[3];
  const float* wkvb  = (const float*)d_in[4];
  const float* wo    = (const float*)d_in[5];
  const float* freqs = (const float*)d_in[6];
  float* out = (float*)d_out;

  char* p = (char*)d_ws;
  auto alloc = [&](size_t bytes) {
    char* r = p;
    p += (bytes + 255) & ~(size_t)255;
    return r;
  };
  bf16*  xb    = (bf16*) alloc((size_t)T_TOK * 1024 * 2);
  bf16*  wqb   = (bf16*) alloc((size_t)2304 * 1024 * 2);
  bf16*  wkvab = (bf16*) alloc((size_t)640 * 1024 * 2);     // padded N 576->640
  bf16*  wbnT  = (bf16*) alloc((size_t)12 * 512 * 128 * 2);
  bf16*  wbv   = (bf16*) alloc((size_t)12 * 128 * 512 * 2);
  bf16*  wob   = (bf16*) alloc((size_t)1024 * 1536 * 2);
  float* kvf   = (float*)alloc((size_t)T_TOK * 576 * 4);
  bf16*  Kp    = (bf16*) alloc((size_t)T_TOK * KLD * 2 + 4096);  // +DMA slack
  bf16*  VpT   = (bf16*) alloc((size_t)12 * 128 * T_TOK * 2);
  bf16*  qn    = (bf16*) alloc((size_t)12 * T_TOK * 128 * 2);
  bf16*  qabs  = (bf16*) alloc((size_t)12 * T_TOK * 576 * 2);
  bf16*  o_all = (bf16*) alloc((size_t)T_TOK * 1536 * 2);

  cast_f32_bf16<<<8192, 256, 0, stream>>>(x, xb, (long)T_TOK * 1024 / 4);
  cast_f32_bf16<<<2304, 256, 0, stream>>>(wq, wqb, (long)2304 * 1024 / 4);
  cast_wkva_pad<<<640, 256, 0, stream>>>(wkva, wkvab);
  split_wkvb<<<6144, 256, 0, stream>>>(wkvb, wbnT, wbv);
  cast_f32_bf16<<<1536, 256, 0, stream>>>(wo, wob, (long)1024 * 1536 / 4);

  // kv_full = x @ wkv_a^T  (fp32 out)
  gemm_bt<0><<<dim3(5, 64, 1), 256, 0, stream>>>(xb, wkvab, (void*)kvf, 576, 1024,
      1024, 1024, 576, 0, 0, 0, nullptr, nullptr, nullptr);
  // q = x @ wq^T, fused rope(q_pe)+scale epilogue -> qn, qabs[512:576]
  gemm_bt<2><<<dim3(18, 64, 1), 256, 0, stream>>>(xb, wqb, nullptr, 2304, 1024,
      1024, 1024, 0, 0, 0, 0, freqs, qn, qabs);
  kvnorm_rope<<<T_TOK, 64, 0, stream>>>(kvf, kvnw, freqs, Kp);
  // VpT[h][d][t] = (kv_c @ wbv[h]^T)^T  (batched over heads, transposed bf16 write)
  gemm_bt<3><<<dim3(1, 64, 12), 256, 0, stream>>>(Kp, wbv, (void*)VpT, 128, 512,
      KLD, 512, T_TOK, 0, (long)128 * 512, (long)128 * T_TOK,
      nullptr, nullptr, nullptr);
  // q_abs[h] = qn[h] @ wbnT[h]^T  (batched over heads, bf16 out into qabs[0:512])
  gemm_bt<1><<<dim3(4, 64, 12), 256, 0, stream>>>(qn, wbnT, (void*)qabs, 512, 128,
      128, 128, 576, (long)T_TOK * 128, (long)512 * 128, (long)T_TOK * 576,
      nullptr, nullptr, nullptr);
  mla_attn<<<dim3(128, 3, 4), 256, 0, stream>>>(qabs, Kp, VpT, o_all);
  // out = o_all @ wo^T (fp32 out)
  gemm_bt<0><<<dim3(8, 64, 1), 256, 0, stream>>>(o_all, wob, (void*)out, 1024, 1536,
      1536, 1536, 1024, 0, 0, 0, nullptr, nullptr, nullptr);
}